// Round 9
// baseline (187.049 us; speedup 1.0000x reference)
//
#include <hip/hip_runtime.h>
#include <hip/hip_bf16.h>
#include <hip/hip_fp16.h>

// GAT 2-layer forward for MI355X — round 9.
// Changes vs round 8:
//  - xph1 stored HEAD-MAJOR [2][N][64] fp16; node1 blocks mapped so head =
//    blockIdx&1 -> heads alternate XCDs (bid%8 round-robin) -> per-XCD L2
//    working set halves (12.8 -> 6.4 MB table per XCD).
//  - node kernels: 128-thr blocks = 2 same-head waves (2 nodes/block).
//  - bucket_scan dispatch removed: bin/build do an in-block 256-wide scan of
//    bucket_count; single memset zeroes count+cursor.

#define SLOPE 0.2f
static __device__ __forceinline__ float lrelu(float a) { return a > 0.f ? a : SLOPE * a; }

#define NBK_MAX 256  // max buckets (N <= 65536)

typedef _Float16 half8 __attribute__((ext_vector_type(8)));
typedef float f32x4 __attribute__((ext_vector_type(4)));

// ---------------- CSR build (bucketed) ----------------

__global__ void bucket_hist(const int* __restrict__ dst, int* __restrict__ bucket_count,
                            int E, int nbk) {
  __shared__ int h[NBK_MAX];
  for (int i = threadIdx.x; i < nbk; i += blockDim.x) h[i] = 0;
  __syncthreads();
  int stride = gridDim.x * blockDim.x;
  for (int e = blockIdx.x * blockDim.x + threadIdx.x; e < E; e += stride)
    atomicAdd(&h[dst[e] >> 8], 1);
  __syncthreads();
  for (int i = threadIdx.x; i < nbk; i += blockDim.x)
    if (h[i]) atomicAdd(&bucket_count[i], h[i]);
}

template <int CHUNK>  // 8192 = 256 threads x 32
__global__ void bin_kernel(const int* __restrict__ src, const int* __restrict__ dst,
                           const int* __restrict__ bucket_count, int* __restrict__ bucket_cursor,
                           unsigned int* __restrict__ binned, int E, int nbk) {
  constexpr int PT = CHUNK / 256;
  __shared__ int hist[NBK_MAX];
  __shared__ int lbase[NBK_MAX];
  __shared__ int lcur[NBK_MAX];
  __shared__ int gpos[NBK_MAX];
  __shared__ unsigned int stage[CHUNK];
  __shared__ int sh[256];
  int t = threadIdx.x;
  int e0 = blockIdx.x * CHUNK;
  int cnt = min(CHUNK, E - e0);

  for (int i = t; i < nbk; i += 256) hist[i] = 0;
  __syncthreads();

  unsigned int pk[PT];
#pragma unroll
  for (int i = 0; i < PT; i++) {
    int e = e0 + t + i * 256;
    if (e < E) {
      int s = src[e], d = dst[e];
      int b = d >> 8;
      pk[i] = ((unsigned)b << 24) | ((unsigned)s << 8) | (unsigned)(d & 255);
      atomicAdd(&hist[b], 1);
    } else {
      pk[i] = 0xFFFFFFFFu;
    }
  }
  __syncthreads();

  // scan 1: local hist -> lbase/lcur
  int hv = (t < nbk) ? hist[t] : 0;
  sh[t] = hv;
  __syncthreads();
  for (int o = 1; o < 256; o <<= 1) {
    int u = (t >= o) ? sh[t - o] : 0;
    __syncthreads();
    sh[t] += u;
    __syncthreads();
  }
  if (t < nbk) {
    lbase[t] = sh[t] - hv;
    lcur[t] = sh[t] - hv;
  }
  __syncthreads();

  // scan 2: global bucket_count -> bucket bases; reserve range
  int gv = (t < nbk) ? bucket_count[t] : 0;
  sh[t] = gv;
  __syncthreads();
  for (int o = 1; o < 256; o <<= 1) {
    int u = (t >= o) ? sh[t - o] : 0;
    __syncthreads();
    sh[t] += u;
    __syncthreads();
  }
  if (t < nbk) {
    int gbase = sh[t] - gv;
    gpos[t] = hv ? (gbase + atomicAdd(&bucket_cursor[t], hv)) : 0;
  }
  __syncthreads();

#pragma unroll
  for (int i = 0; i < PT; i++) {
    if (pk[i] != 0xFFFFFFFFu) {
      int b = pk[i] >> 24;
      int lp = atomicAdd(&lcur[b], 1);
      stage[lp] = pk[i];
    }
  }
  __syncthreads();

  for (int i = t; i < cnt; i += 256) {
    unsigned int v = stage[i];
    int b = v >> 24;
    binned[gpos[b] + (i - lbase[b])] = v;
  }
}

template <int CAP>  // 12288
__global__ void build_kernel(const unsigned int* __restrict__ binned,
                             const int* __restrict__ bucket_count, int* __restrict__ offsets,
                             int* __restrict__ csr_src, int Nn, int Etot, int nbk) {
  __shared__ int nhist[256];
  __shared__ int sh[256];
  __shared__ int lcur[256];
  __shared__ int sbase, ssz;
  __shared__ unsigned short stage[CAP];
  int b = blockIdx.x;
  int t = threadIdx.x;

  // in-block scan of bucket_count -> this bucket's base/size
  int gv = (t < nbk) ? bucket_count[t] : 0;
  sh[t] = gv;
  __syncthreads();
  for (int o = 1; o < 256; o <<= 1) {
    int u = (t >= o) ? sh[t - o] : 0;
    __syncthreads();
    sh[t] += u;
    __syncthreads();
  }
  if (t == b) { sbase = sh[t] - gv; ssz = gv; }
  __syncthreads();
  int base = sbase;
  int sz = ssz;

  nhist[t] = 0;
  __syncthreads();
  for (int i = t; i < sz; i += 256) atomicAdd(&nhist[binned[base + i] & 255], 1);
  __syncthreads();

  int hv = nhist[t];
  sh[t] = hv;
  __syncthreads();
  for (int o = 1; o < 256; o <<= 1) {
    int u = (t >= o) ? sh[t - o] : 0;
    __syncthreads();
    sh[t] += u;
    __syncthreads();
  }
  int excl = sh[t] - hv;
  int node = (b << 8) + t;
  if (node < Nn) offsets[node] = base + excl;
  if (b == nbk - 1 && t == 0) offsets[Nn] = Etot;
  lcur[t] = excl;
  __syncthreads();

  if (sz <= CAP) {
    for (int i = t; i < sz; i += 256) {
      unsigned int v = binned[base + i];
      int lp = atomicAdd(&lcur[v & 255], 1);
      stage[lp] = (unsigned short)((v >> 8) & 0xFFFFu);
    }
    __syncthreads();
    for (int i = t; i < sz; i += 256) csr_src[base + i] = (int)stage[i];
  } else {
    for (int i = t; i < sz; i += 256) {
      unsigned int v = binned[base + i];
      int lp = atomicAdd(&lcur[v & 255], 1);
      csr_src[base + lp] = (int)((v >> 8) & 0xFFFFu);
    }
  }
}

// ---------------- weight transpose to fp16 ----------------

__global__ void xpose_w(const float* __restrict__ W1, const float* __restrict__ W2,
                        __half* __restrict__ WT1, __half* __restrict__ WT2) {
  int t = threadIdx.x;
  if (blockIdx.x == 0) {
    for (int idx = t; idx < 128 * 128; idx += 256) {
      int c = idx >> 7, k = idx & 127;
      WT1[idx] = __float2half(W1[k * 128 + c]);
    }
  } else {
    for (int idx = t; idx < 64 * 128; idx += 256) {
      int c = idx >> 7, k = idx & 127;
      WT2[idx] = __float2half(W2[k * 64 + c]);
    }
  }
}

// ---------------- MFMA GEMM + fused attention dots ----------------

// Y stored HEAD-MAJOR: [H][M][64] fp16 (for H=1 identical to row-major [M][64]).
template <int K, int NOUT, int H, typename AT>
__global__ __launch_bounds__(256) void gemm_att_mfma(
    const AT* __restrict__ A, const __half* __restrict__ WTg,
    const float* __restrict__ att_s, const float* __restrict__ att_d,
    __half* __restrict__ Y, float* __restrict__ AS, float* __restrict__ AD, int M) {
  constexpr int KK = K / 32;
  constexpr int NT = NOUT / 16;
  constexpr int NTH = NT / H;
  constexpr int LDW = K + 8;
  constexpr int LDY = NOUT + 8;
  __shared__ __half wts[NOUT * LDW];
  __shared__ __half ylds[4][16 * LDY];

  int tid = threadIdx.x;
  int w = tid >> 6;
  int lane = tid & 63;
  int lrow = lane & 15;
  int lch = lane >> 4;
  int r0w = blockIdx.x * 64 + w * 16;
  bool active = (r0w < M);

  constexpr int RCH = K / 8;
  for (int idx = tid; idx < NOUT * RCH; idx += 256) {
    int c = idx / RCH, ch = idx % RCH;
    *(uint4*)&wts[c * LDW + ch * 8] = ((const uint4*)WTg)[idx];
  }
  __syncthreads();

  f32x4 acc[NT];
#pragma unroll
  for (int nt = 0; nt < NT; nt++) acc[nt] = (f32x4){0.f, 0.f, 0.f, 0.f};

  if (active) {
    half8 afrag[KK];
    if constexpr (sizeof(AT) == 4) {
      const float* arow = (const float*)A + (size_t)(r0w + lrow) * K + lch * 8;
#pragma unroll
      for (int kk = 0; kk < KK; kk++) {
        float4 v0 = *(const float4*)(arow + kk * 32);
        float4 v1 = *(const float4*)(arow + kk * 32 + 4);
        half8 a;
        a[0] = (_Float16)v0.x; a[1] = (_Float16)v0.y;
        a[2] = (_Float16)v0.z; a[3] = (_Float16)v0.w;
        a[4] = (_Float16)v1.x; a[5] = (_Float16)v1.y;
        a[6] = (_Float16)v1.z; a[7] = (_Float16)v1.w;
        afrag[kk] = a;
      }
    } else {
      const __half* arow = (const __half*)A + (size_t)(r0w + lrow) * K + lch * 8;
#pragma unroll
      for (int kk = 0; kk < KK; kk++) afrag[kk] = *(const half8*)(arow + kk * 32);
    }

#pragma unroll
    for (int kk = 0; kk < KK; kk++) {
#pragma unroll
      for (int nt = 0; nt < NT; nt++) {
        half8 b = *(const half8*)&wts[(nt * 16 + lrow) * LDW + kk * 32 + lch * 8];
        acc[nt] = __builtin_amdgcn_mfma_f32_16x16x32_f16(afrag[kk], b, acc[nt], 0, 0, 0);
      }
    }

    float asw[NT], adw[NT];
#pragma unroll
    for (int nt = 0; nt < NT; nt++) {
      asw[nt] = att_s[nt * 16 + lrow];
      adw[nt] = att_d[nt * 16 + lrow];
    }
#pragma unroll
    for (int h = 0; h < H; h++) {
#pragma unroll
      for (int reg = 0; reg < 4; reg++) {
        float ps = 0.f, pd = 0.f;
#pragma unroll
        for (int nt = h * NTH; nt < (h + 1) * NTH; nt++) {
          ps = fmaf(acc[nt][reg], asw[nt], ps);
          pd = fmaf(acc[nt][reg], adw[nt], pd);
        }
#pragma unroll
        for (int o = 1; o < 16; o <<= 1) {
          ps += __shfl_xor(ps, o);
          pd += __shfl_xor(pd, o);
        }
        if (lrow == 0) {
          int row = r0w + lch * 4 + reg;
          AS[row * H + h] = ps;
          AD[row * H + h] = pd;
        }
      }
    }

#pragma unroll
    for (int nt = 0; nt < NT; nt++) {
#pragma unroll
      for (int reg = 0; reg < 4; reg++) {
        ylds[w][(lch * 4 + reg) * LDY + nt * 16 + lrow] = __float2half(acc[nt][reg]);
      }
    }
  }
  __syncthreads();

  if (active) {
    // head-major store: chunk ch -> head = ch>>3, sub-chunk = ch&7
    constexpr int YCH = NOUT / 8;
    for (int idx = lane; idx < 16 * YCH; idx += 64) {
      int row = idx / YCH, ch = idx % YCH;
      int head = ch >> 3;
      uint4 v = *(const uint4*)&ylds[w][row * LDY + ch * 8];
      *(uint4*)(Y + ((size_t)head * M + r0w + row) * 64 + (ch & 7) * 8) = v;
    }
  }
}

// ---------------- node softmax + aggregate ----------------

static __device__ __forceinline__ void fma8(uint4 u, float e, float* __restrict__ acc) {
  float2 f0 = __half22float2(*(const __half2*)&u.x);
  float2 f1 = __half22float2(*(((const __half2*)&u.x) + 1));
  float2 f2 = __half22float2(*(const __half2*)&u.z);
  float2 f3 = __half22float2(*(((const __half2*)&u.z) + 1));
  acc[0] = fmaf(e, f0.x, acc[0]); acc[1] = fmaf(e, f0.y, acc[1]);
  acc[2] = fmaf(e, f1.x, acc[2]); acc[3] = fmaf(e, f1.y, acc[3]);
  acc[4] = fmaf(e, f2.x, acc[4]); acc[5] = fmaf(e, f2.y, acc[5]);
  acc[6] = fmaf(e, f3.x, acc[6]); acc[7] = fmaf(e, f3.y, acc[7]);
}

static __device__ __forceinline__ void pk4(uint4 u, unsigned ep, __half2* __restrict__ acc2) {
  __half2 e2 = *(const __half2*)&ep;
  acc2[0] = __hfma2(e2, *(const __half2*)&u.x, acc2[0]);
  acc2[1] = __hfma2(e2, *(((const __half2*)&u.x) + 1), acc2[1]);
  acc2[2] = __hfma2(e2, *(const __half2*)&u.z, acc2[2]);
  acc2[3] = __hfma2(e2, *(((const __half2*)&u.z) + 1), acc2[3]);
}

// 128-thr blocks = 2 same-head waves (2 consecutive nodes).
// H=2: head = blockIdx&1 (alternates XCDs via bid%8 round-robin), nodes
// (bid>>1)*2 + wave. H=1: head 0, nodes bid*2 + wave.
// Feature table per head: XPH + head*M*64 ([M][64] fp16, 128 B rows).
template <int H, bool RELU, typename OT>
__global__ void node_kernel(const int* __restrict__ offsets, const int* __restrict__ csr_src,
                            const float* __restrict__ AS, const float* __restrict__ AD,
                            const __half* __restrict__ XPH, const float* __restrict__ bias,
                            OT* __restrict__ OUT, int Nn) {
  constexpr int C = 64;
  int w = threadIdx.x >> 6;
  int bid = blockIdx.x;
  int h = (H == 2) ? (bid & 1) : 0;
  int n = (H == 2) ? ((bid >> 1) * 2 + w) : (bid * 2 + w);
  if (n >= Nn) return;  // wave-uniform
  int lane = threadIdx.x & 63;
  int g = lane >> 3;
  int sub = lane & 7;

  int beg = offsets[n], end = offsets[n + 1];
  int deg = end - beg;

  float ad_n = AD[n * H + h];
  const __half* base = XPH + (size_t)h * Nn * C + sub * 8;

  float acc[8];
#pragma unroll
  for (int k = 0; k < 8; k++) acc[k] = 0.f;
  float z = 0.f;

  float e_self = __expf(lrelu(AS[n * H + h] + ad_n));
  if (g == 0) {
    uint4 u = *(const uint4*)(base + (size_t)n * C);
    fma8(u, e_self, acc);
  }
  if (lane == 0) z = e_self;

  for (int i0 = 0; i0 < deg; i0 += 64) {
    int cnt = min(64, deg - i0);
    int srcv = 0;
    float ev = 0.f;
    int epk = 0;
    if (lane < cnt) {
      srcv = csr_src[beg + i0 + lane];
      ev = __expf(lrelu(AS[srcv * H + h] + ad_n));
      __half eh = __float2half(ev);
      unsigned short us = *(const unsigned short*)&eh;
      epk = (int)(((unsigned)us << 16) | us);
    }
    z += ev;
    int j = 0;
    for (; j + 32 <= cnt; j += 32) {
      int s0 = __shfl(srcv, j + g),      s1 = __shfl(srcv, j + 8 + g);
      int s2 = __shfl(srcv, j + 16 + g), s3 = __shfl(srcv, j + 24 + g);
      int p0 = __shfl(epk, j + g),       p1 = __shfl(epk, j + 8 + g);
      int p2 = __shfl(epk, j + 16 + g),  p3 = __shfl(epk, j + 24 + g);
      uint4 u0 = *(const uint4*)(base + (size_t)s0 * C);
      uint4 u1 = *(const uint4*)(base + (size_t)s1 * C);
      uint4 u2 = *(const uint4*)(base + (size_t)s2 * C);
      uint4 u3 = *(const uint4*)(base + (size_t)s3 * C);
      __half2 acc2[4];
      acc2[0] = __half2(__half(0.f), __half(0.f));
      acc2[1] = acc2[0]; acc2[2] = acc2[0]; acc2[3] = acc2[0];
      pk4(u0, (unsigned)p0, acc2);
      pk4(u1, (unsigned)p1, acc2);
      pk4(u2, (unsigned)p2, acc2);
      pk4(u3, (unsigned)p3, acc2);
#pragma unroll
      for (int k = 0; k < 4; k++) {
        float2 f = __half22float2(acc2[k]);
        acc[2 * k] += f.x;
        acc[2 * k + 1] += f.y;
      }
    }
    for (; j + 8 <= cnt; j += 8) {
      int s = __shfl(srcv, j + g);
      float e = __shfl(ev, j + g);
      uint4 u = *(const uint4*)(base + (size_t)s * C);
      fma8(u, e, acc);
    }
    if (j < cnt) {
      int idx = j + g;
      int s = __shfl(srcv, idx & 63);
      float e = __shfl(ev, idx & 63);
      if (idx < cnt) {
        uint4 u = *(const uint4*)(base + (size_t)s * C);
        fma8(u, e, acc);
      }
    }
  }

#pragma unroll
  for (int o = 8; o <= 32; o <<= 1) {
#pragma unroll
    for (int k = 0; k < 8; k++) acc[k] += __shfl_xor(acc[k], o);
  }
  for (int o = 32; o > 0; o >>= 1) z += __shfl_xor(z, o);
  float inv = 1.0f / z;

  if (g == 0) {
    const float* bp = bias + h * C + sub * 8;
    float r[8];
#pragma unroll
    for (int k = 0; k < 8; k++) {
      r[k] = fmaf(acc[k], inv, bp[k]);
      if (RELU) r[k] = fmaxf(r[k], 0.f);
    }
    if constexpr (sizeof(OT) == 4) {
      float* op = (float*)OUT + (size_t)n * (H * C) + h * C + sub * 8;
      ((float4*)op)[0] = make_float4(r[0], r[1], r[2], r[3]);
      ((float4*)op)[1] = make_float4(r[4], r[5], r[6], r[7]);
    } else {
      __half* op = (__half*)OUT + (size_t)n * (H * C) + h * C + sub * 8;
      __half2 h0 = __floats2half2_rn(r[0], r[1]);
      __half2 h1 = __floats2half2_rn(r[2], r[3]);
      __half2 h2 = __floats2half2_rn(r[4], r[5]);
      __half2 h3 = __floats2half2_rn(r[6], r[7]);
      uint4 u;
      u.x = *(unsigned int*)&h0; u.y = *(unsigned int*)&h1;
      u.z = *(unsigned int*)&h2; u.w = *(unsigned int*)&h3;
      *(uint4*)op = u;
    }
  }
}

// ---------------- launch ----------------

static inline size_t alignup(size_t x) { return (x + 255) & ~(size_t)255; }

extern "C" void kernel_launch(void* const* d_in, const int* in_sizes, int n_in,
                              void* d_out, int out_size, void* d_ws, size_t ws_size,
                              hipStream_t stream) {
  const float* x    = (const float*)d_in[0];
  const int*   edges= (const int*)d_in[1];
  const float* W1   = (const float*)d_in[2];
  const float* as1w = (const float*)d_in[3];
  const float* ad1w = (const float*)d_in[4];
  const float* b1   = (const float*)d_in[5];
  const float* W2   = (const float*)d_in[6];
  const float* as2w = (const float*)d_in[7];
  const float* ad2w = (const float*)d_in[8];
  const float* b2   = (const float*)d_in[9];

  const int N = in_sizes[0] / 128;   // 50000
  const int E = in_sizes[1] / 2;     // 1600000
  const int* src = edges;
  const int* dst = edges + E;
  const int nbk = (N + 255) >> 8;    // 196 buckets

  char* p = (char*)d_ws;
  size_t off = 0;
  auto take = [&](size_t bytes) { char* r = p + off; off = alignup(off + bytes); return r; };
  __half* xph1 = (__half*)take((size_t)N * 128 * 2);  // head-major [2][N][64]
  __half* xph2 = (__half*)take((size_t)N * 64 * 2);
  __half* hbuf = (__half*)take((size_t)N * 128 * 2);
  __half* wt1  = (__half*)take((size_t)128 * 128 * 2);
  __half* wt2  = (__half*)take((size_t)64 * 128 * 2);
  float* as1   = (float*)take((size_t)N * 2 * 4);
  float* ad1   = (float*)take((size_t)N * 2 * 4);
  float* as2   = (float*)take((size_t)N * 4);
  float* ad2   = (float*)take((size_t)N * 4);
  int* offsets = (int*)take((size_t)(N + 1) * 4);
  int* csr_src = (int*)take((size_t)E * 4);
  unsigned int* binned = (unsigned int*)take((size_t)E * 4);
  int* bzero   = (int*)take((size_t)2 * (nbk + 1) * 4);  // bcount | bcursor
  int* bcount  = bzero;
  int* bcursor = bzero + (nbk + 1);
  (void)ws_size;

  constexpr int CHUNK = 8192;
  const int binBlocks = (E + CHUNK - 1) / CHUNK;
  const int gemmBlocks = (N + 63) / 64;

  hipMemsetAsync(bzero, 0, (size_t)2 * (nbk + 1) * 4, stream);
  bucket_hist<<<392, 256, 0, stream>>>(dst, bcount, E, nbk);
  bin_kernel<CHUNK><<<binBlocks, 256, 0, stream>>>(src, dst, bcount, bcursor, binned, E, nbk);
  build_kernel<12288><<<nbk, 256, 0, stream>>>(binned, bcount, offsets, csr_src, N, E, nbk);

  xpose_w<<<2, 256, 0, stream>>>(W1, W2, wt1, wt2);

  // layer 1 (H=2, C=64, ReLU): x fp32 -> MFMA -> head-major xph1 + as1/ad1
  gemm_att_mfma<128, 128, 2, float><<<gemmBlocks, 256, 0, stream>>>(
      x, wt1, as1w, ad1w, xph1, as1, ad1, N);
  node_kernel<2, true, __half><<<N, 128, 0, stream>>>(
      offsets, csr_src, as1, ad1, xph1, b1, hbuf, N);

  // layer 2 (H=1, C=64)
  gemm_att_mfma<128, 64, 1, __half><<<gemmBlocks, 256, 0, stream>>>(
      hbuf, wt2, as2w, ad2w, xph2, as2, ad2, N);
  node_kernel<1, false, float><<<(N + 1) / 2, 128, 0, stream>>>(
      offsets, csr_src, as2, ad2, xph2, b2, (float*)d_out, N);
}

// Round 10
// 175.575 us; speedup vs baseline: 1.0654x; 1.0654x over previous
//
#include <hip/hip_runtime.h>
#include <hip/hip_bf16.h>
#include <hip/hip_fp16.h>

// GAT 2-layer forward for MI355X — round 10.
// Changes vs round 9:
//  - node1 MERGED HEADS: xph1 row-major [N][128] fp16 (256B row); ONE wave per
//    node processes each edge once (16 lanes/edge: lanes 0-7 head0, 8-15 head1).
//    Halves wave-edge-visits (3.3M->1.65M), AS gathers become one float2 load.
//  - node2 reverted to 64-thr 1-node blocks (r9's 2-node coupling cost ~4us).
//  - gemm1 Y store back to row-major.

#define SLOPE 0.2f
static __device__ __forceinline__ float lrelu(float a) { return a > 0.f ? a : SLOPE * a; }

#define NBK_MAX 256  // max buckets (N <= 65536)

typedef _Float16 half8 __attribute__((ext_vector_type(8)));
typedef float f32x4 __attribute__((ext_vector_type(4)));

// ---------------- CSR build (bucketed) ----------------

__global__ void bucket_hist(const int* __restrict__ dst, int* __restrict__ bucket_count,
                            int E, int nbk) {
  __shared__ int h[NBK_MAX];
  for (int i = threadIdx.x; i < nbk; i += blockDim.x) h[i] = 0;
  __syncthreads();
  int stride = gridDim.x * blockDim.x;
  for (int e = blockIdx.x * blockDim.x + threadIdx.x; e < E; e += stride)
    atomicAdd(&h[dst[e] >> 8], 1);
  __syncthreads();
  for (int i = threadIdx.x; i < nbk; i += blockDim.x)
    if (h[i]) atomicAdd(&bucket_count[i], h[i]);
}

template <int CHUNK>  // 8192 = 256 threads x 32
__global__ void bin_kernel(const int* __restrict__ src, const int* __restrict__ dst,
                           const int* __restrict__ bucket_count, int* __restrict__ bucket_cursor,
                           unsigned int* __restrict__ binned, int E, int nbk) {
  constexpr int PT = CHUNK / 256;
  __shared__ int hist[NBK_MAX];
  __shared__ int lbase[NBK_MAX];
  __shared__ int lcur[NBK_MAX];
  __shared__ int gpos[NBK_MAX];
  __shared__ unsigned int stage[CHUNK];
  __shared__ int sh[256];
  int t = threadIdx.x;
  int e0 = blockIdx.x * CHUNK;
  int cnt = min(CHUNK, E - e0);

  for (int i = t; i < nbk; i += 256) hist[i] = 0;
  __syncthreads();

  unsigned int pk[PT];
#pragma unroll
  for (int i = 0; i < PT; i++) {
    int e = e0 + t + i * 256;
    if (e < E) {
      int s = src[e], d = dst[e];
      int b = d >> 8;
      pk[i] = ((unsigned)b << 24) | ((unsigned)s << 8) | (unsigned)(d & 255);
      atomicAdd(&hist[b], 1);
    } else {
      pk[i] = 0xFFFFFFFFu;
    }
  }
  __syncthreads();

  int hv = (t < nbk) ? hist[t] : 0;
  sh[t] = hv;
  __syncthreads();
  for (int o = 1; o < 256; o <<= 1) {
    int u = (t >= o) ? sh[t - o] : 0;
    __syncthreads();
    sh[t] += u;
    __syncthreads();
  }
  if (t < nbk) {
    lbase[t] = sh[t] - hv;
    lcur[t] = sh[t] - hv;
  }
  __syncthreads();

  int gv = (t < nbk) ? bucket_count[t] : 0;
  sh[t] = gv;
  __syncthreads();
  for (int o = 1; o < 256; o <<= 1) {
    int u = (t >= o) ? sh[t - o] : 0;
    __syncthreads();
    sh[t] += u;
    __syncthreads();
  }
  if (t < nbk) {
    int gbase = sh[t] - gv;
    gpos[t] = hv ? (gbase + atomicAdd(&bucket_cursor[t], hv)) : 0;
  }
  __syncthreads();

#pragma unroll
  for (int i = 0; i < PT; i++) {
    if (pk[i] != 0xFFFFFFFFu) {
      int b = pk[i] >> 24;
      int lp = atomicAdd(&lcur[b], 1);
      stage[lp] = pk[i];
    }
  }
  __syncthreads();

  for (int i = t; i < cnt; i += 256) {
    unsigned int v = stage[i];
    int b = v >> 24;
    binned[gpos[b] + (i - lbase[b])] = v;
  }
}

template <int CAP>  // 12288
__global__ void build_kernel(const unsigned int* __restrict__ binned,
                             const int* __restrict__ bucket_count, int* __restrict__ offsets,
                             int* __restrict__ csr_src, int Nn, int Etot, int nbk) {
  __shared__ int nhist[256];
  __shared__ int sh[256];
  __shared__ int lcur[256];
  __shared__ int sbase, ssz;
  __shared__ unsigned short stage[CAP];
  int b = blockIdx.x;
  int t = threadIdx.x;

  int gv = (t < nbk) ? bucket_count[t] : 0;
  sh[t] = gv;
  __syncthreads();
  for (int o = 1; o < 256; o <<= 1) {
    int u = (t >= o) ? sh[t - o] : 0;
    __syncthreads();
    sh[t] += u;
    __syncthreads();
  }
  if (t == b) { sbase = sh[t] - gv; ssz = gv; }
  __syncthreads();
  int base = sbase;
  int sz = ssz;

  nhist[t] = 0;
  __syncthreads();
  for (int i = t; i < sz; i += 256) atomicAdd(&nhist[binned[base + i] & 255], 1);
  __syncthreads();

  int hv = nhist[t];
  sh[t] = hv;
  __syncthreads();
  for (int o = 1; o < 256; o <<= 1) {
    int u = (t >= o) ? sh[t - o] : 0;
    __syncthreads();
    sh[t] += u;
    __syncthreads();
  }
  int excl = sh[t] - hv;
  int node = (b << 8) + t;
  if (node < Nn) offsets[node] = base + excl;
  if (b == nbk - 1 && t == 0) offsets[Nn] = Etot;
  lcur[t] = excl;
  __syncthreads();

  if (sz <= CAP) {
    for (int i = t; i < sz; i += 256) {
      unsigned int v = binned[base + i];
      int lp = atomicAdd(&lcur[v & 255], 1);
      stage[lp] = (unsigned short)((v >> 8) & 0xFFFFu);
    }
    __syncthreads();
    for (int i = t; i < sz; i += 256) csr_src[base + i] = (int)stage[i];
  } else {
    for (int i = t; i < sz; i += 256) {
      unsigned int v = binned[base + i];
      int lp = atomicAdd(&lcur[v & 255], 1);
      csr_src[base + lp] = (int)((v >> 8) & 0xFFFFu);
    }
  }
}

// ---------------- weight transpose to fp16 ----------------

__global__ void xpose_w(const float* __restrict__ W1, const float* __restrict__ W2,
                        __half* __restrict__ WT1, __half* __restrict__ WT2) {
  int t = threadIdx.x;
  if (blockIdx.x == 0) {
    for (int idx = t; idx < 128 * 128; idx += 256) {
      int c = idx >> 7, k = idx & 127;
      WT1[idx] = __float2half(W1[k * 128 + c]);
    }
  } else {
    for (int idx = t; idx < 64 * 128; idx += 256) {
      int c = idx >> 7, k = idx & 127;
      WT2[idx] = __float2half(W2[k * 64 + c]);
    }
  }
}

// ---------------- MFMA GEMM + fused attention dots ----------------

template <int K, int NOUT, int H, typename AT>
__global__ __launch_bounds__(256) void gemm_att_mfma(
    const AT* __restrict__ A, const __half* __restrict__ WTg,
    const float* __restrict__ att_s, const float* __restrict__ att_d,
    __half* __restrict__ Y, float* __restrict__ AS, float* __restrict__ AD, int M) {
  constexpr int KK = K / 32;
  constexpr int NT = NOUT / 16;
  constexpr int NTH = NT / H;
  constexpr int LDW = K + 8;
  constexpr int LDY = NOUT + 8;
  __shared__ __half wts[NOUT * LDW];
  __shared__ __half ylds[4][16 * LDY];

  int tid = threadIdx.x;
  int w = tid >> 6;
  int lane = tid & 63;
  int lrow = lane & 15;
  int lch = lane >> 4;
  int r0w = blockIdx.x * 64 + w * 16;
  bool active = (r0w < M);

  constexpr int RCH = K / 8;
  for (int idx = tid; idx < NOUT * RCH; idx += 256) {
    int c = idx / RCH, ch = idx % RCH;
    *(uint4*)&wts[c * LDW + ch * 8] = ((const uint4*)WTg)[idx];
  }
  __syncthreads();

  f32x4 acc[NT];
#pragma unroll
  for (int nt = 0; nt < NT; nt++) acc[nt] = (f32x4){0.f, 0.f, 0.f, 0.f};

  if (active) {
    half8 afrag[KK];
    if constexpr (sizeof(AT) == 4) {
      const float* arow = (const float*)A + (size_t)(r0w + lrow) * K + lch * 8;
#pragma unroll
      for (int kk = 0; kk < KK; kk++) {
        float4 v0 = *(const float4*)(arow + kk * 32);
        float4 v1 = *(const float4*)(arow + kk * 32 + 4);
        half8 a;
        a[0] = (_Float16)v0.x; a[1] = (_Float16)v0.y;
        a[2] = (_Float16)v0.z; a[3] = (_Float16)v0.w;
        a[4] = (_Float16)v1.x; a[5] = (_Float16)v1.y;
        a[6] = (_Float16)v1.z; a[7] = (_Float16)v1.w;
        afrag[kk] = a;
      }
    } else {
      const __half* arow = (const __half*)A + (size_t)(r0w + lrow) * K + lch * 8;
#pragma unroll
      for (int kk = 0; kk < KK; kk++) afrag[kk] = *(const half8*)(arow + kk * 32);
    }

#pragma unroll
    for (int kk = 0; kk < KK; kk++) {
#pragma unroll
      for (int nt = 0; nt < NT; nt++) {
        half8 b = *(const half8*)&wts[(nt * 16 + lrow) * LDW + kk * 32 + lch * 8];
        acc[nt] = __builtin_amdgcn_mfma_f32_16x16x32_f16(afrag[kk], b, acc[nt], 0, 0, 0);
      }
    }

    float asw[NT], adw[NT];
#pragma unroll
    for (int nt = 0; nt < NT; nt++) {
      asw[nt] = att_s[nt * 16 + lrow];
      adw[nt] = att_d[nt * 16 + lrow];
    }
#pragma unroll
    for (int h = 0; h < H; h++) {
#pragma unroll
      for (int reg = 0; reg < 4; reg++) {
        float ps = 0.f, pd = 0.f;
#pragma unroll
        for (int nt = h * NTH; nt < (h + 1) * NTH; nt++) {
          ps = fmaf(acc[nt][reg], asw[nt], ps);
          pd = fmaf(acc[nt][reg], adw[nt], pd);
        }
#pragma unroll
        for (int o = 1; o < 16; o <<= 1) {
          ps += __shfl_xor(ps, o);
          pd += __shfl_xor(pd, o);
        }
        if (lrow == 0) {
          int row = r0w + lch * 4 + reg;
          AS[row * H + h] = ps;
          AD[row * H + h] = pd;
        }
      }
    }

#pragma unroll
    for (int nt = 0; nt < NT; nt++) {
#pragma unroll
      for (int reg = 0; reg < 4; reg++) {
        ylds[w][(lch * 4 + reg) * LDY + nt * 16 + lrow] = __float2half(acc[nt][reg]);
      }
    }
  }
  __syncthreads();

  if (active) {
    constexpr int YCH = NOUT / 8;
    for (int idx = lane; idx < 16 * YCH; idx += 64) {
      int row = idx / YCH, ch = idx % YCH;
      uint4 v = *(const uint4*)&ylds[w][row * LDY + ch * 8];
      *(uint4*)(Y + (size_t)(r0w + row) * NOUT + ch * 8) = v;
    }
  }
}

// ---------------- node softmax + aggregate ----------------

static __device__ __forceinline__ void fma8(uint4 u, float e, float* __restrict__ acc) {
  float2 f0 = __half22float2(*(const __half2*)&u.x);
  float2 f1 = __half22float2(*(((const __half2*)&u.x) + 1));
  float2 f2 = __half22float2(*(const __half2*)&u.z);
  float2 f3 = __half22float2(*(((const __half2*)&u.z) + 1));
  acc[0] = fmaf(e, f0.x, acc[0]); acc[1] = fmaf(e, f0.y, acc[1]);
  acc[2] = fmaf(e, f1.x, acc[2]); acc[3] = fmaf(e, f1.y, acc[3]);
  acc[4] = fmaf(e, f2.x, acc[4]); acc[5] = fmaf(e, f2.y, acc[5]);
  acc[6] = fmaf(e, f3.x, acc[6]); acc[7] = fmaf(e, f3.y, acc[7]);
}

static __device__ __forceinline__ void pk4(uint4 u, unsigned ep, __half2* __restrict__ acc2) {
  __half2 e2 = *(const __half2*)&ep;
  acc2[0] = __hfma2(e2, *(const __half2*)&u.x, acc2[0]);
  acc2[1] = __hfma2(e2, *(((const __half2*)&u.x) + 1), acc2[1]);
  acc2[2] = __hfma2(e2, *(const __half2*)&u.z, acc2[2]);
  acc2[3] = __hfma2(e2, *(((const __half2*)&u.z) + 1), acc2[3]);
}

// One wave (64 thr) per node. H=2: 16 lanes/edge (lanes 0-7 head0 channels,
// 8-15 head1), 4 edge-groups; each edge visited ONCE for both heads.
// H=1: 8 lanes/edge, 8 edge-groups. 4 gathers in flight per unrolled iter.
template <int H, bool RELU, typename OT>
__global__ void node_kernel(const int* __restrict__ offsets, const int* __restrict__ csr_src,
                            const float* __restrict__ AS, const float* __restrict__ AD,
                            const __half* __restrict__ XPH, const float* __restrict__ bias,
                            OT* __restrict__ OUT, int Nn) {
  constexpr int ROWH = H * 64;           // halfs per feature row
  constexpr int LPE = (H == 2) ? 16 : 8; // lanes per edge
  constexpr int G = 64 / LPE;            // edge groups per wave
  int n = blockIdx.x;
  int lane = threadIdx.x & 63;
  int g = lane / LPE;
  int sub = lane & (LPE - 1);

  int beg = offsets[n], end = offsets[n + 1];
  int deg = end - beg;

  const __half* base = XPH + sub * 8;

  float acc[8];
#pragma unroll
  for (int k = 0; k < 8; k++) acc[k] = 0.f;
  float z0 = 0.f, z1 = 0.f;

  float ad0, ad1 = 0.f;
  if constexpr (H == 2) {
    float2 adn = ((const float2*)AD)[n];
    ad0 = adn.x; ad1 = adn.y;
  } else {
    ad0 = AD[n];
  }

  // self-loop
  if constexpr (H == 2) {
    float2 asn = ((const float2*)AS)[n];
    float es0 = __expf(lrelu(asn.x + ad0));
    float es1 = __expf(lrelu(asn.y + ad1));
    if (g == 0) {
      uint4 u = *(const uint4*)(base + (size_t)n * ROWH);
      fma8(u, (lane & 8) ? es1 : es0, acc);
    }
    if (lane == 0) { z0 = es0; z1 = es1; }
  } else {
    float es = __expf(lrelu(AS[n] + ad0));
    if (g == 0) {
      uint4 u = *(const uint4*)(base + (size_t)n * ROWH);
      fma8(u, es, acc);
    }
    if (lane == 0) z0 = es;
  }

  for (int i0 = 0; i0 < deg; i0 += 64) {
    int cnt = min(64, deg - i0);
    int srcv = 0;
    int epk = 0;
    float ev0 = 0.f, ev1 = 0.f;
    if (lane < cnt) {
      srcv = csr_src[beg + i0 + lane];
      if constexpr (H == 2) {
        float2 asv = ((const float2*)AS)[srcv];
        ev0 = __expf(lrelu(asv.x + ad0));
        ev1 = __expf(lrelu(asv.y + ad1));
        __half h0 = __float2half(ev0), h1 = __float2half(ev1);
        epk = (int)(((unsigned)*(unsigned short*)&h1 << 16) | *(unsigned short*)&h0);
      } else {
        ev0 = __expf(lrelu(AS[srcv] + ad0));
        __half h0 = __float2half(ev0);
        unsigned short us = *(unsigned short*)&h0;
        epk = (int)(((unsigned)us << 16) | us);
      }
    }
    z0 += ev0;
    if constexpr (H == 2) z1 += ev1;

    // per-lane head-select of packed e (dup into both half2 slots)
    auto sel = [&](int p) -> unsigned {
      unsigned short us;
      if constexpr (H == 2)
        us = (lane & 8) ? (unsigned short)((unsigned)p >> 16) : (unsigned short)((unsigned)p & 0xFFFFu);
      else
        us = (unsigned short)((unsigned)p & 0xFFFFu);
      return ((unsigned)us << 16) | us;
    };

    int j = 0;
    for (; j + 4 * G <= cnt; j += 4 * G) {
      int s0 = __shfl(srcv, j + g),         s1 = __shfl(srcv, j + G + g);
      int s2 = __shfl(srcv, j + 2 * G + g), s3 = __shfl(srcv, j + 3 * G + g);
      int p0 = __shfl(epk, j + g),          p1 = __shfl(epk, j + G + g);
      int p2 = __shfl(epk, j + 2 * G + g),  p3 = __shfl(epk, j + 3 * G + g);
      uint4 u0 = *(const uint4*)(base + (size_t)s0 * ROWH);
      uint4 u1 = *(const uint4*)(base + (size_t)s1 * ROWH);
      uint4 u2 = *(const uint4*)(base + (size_t)s2 * ROWH);
      uint4 u3 = *(const uint4*)(base + (size_t)s3 * ROWH);
      __half2 acc2[4];
      acc2[0] = __half2(__half(0.f), __half(0.f));
      acc2[1] = acc2[0]; acc2[2] = acc2[0]; acc2[3] = acc2[0];
      pk4(u0, sel(p0), acc2);
      pk4(u1, sel(p1), acc2);
      pk4(u2, sel(p2), acc2);
      pk4(u3, sel(p3), acc2);
#pragma unroll
      for (int k = 0; k < 4; k++) {
        float2 f = __half22float2(acc2[k]);
        acc[2 * k] += f.x;
        acc[2 * k + 1] += f.y;
      }
    }
    for (; j + G <= cnt; j += G) {
      int s = __shfl(srcv, j + g);
      int p = __shfl(epk, j + g);
      __half_raw hr; hr.x = (unsigned short)(sel(p) & 0xFFFFu);
      float e = __half2float(__half(hr));
      uint4 u = *(const uint4*)(base + (size_t)s * ROWH);
      fma8(u, e, acc);
    }
    if (j < cnt) {
      int idx = j + g;
      int s = __shfl(srcv, idx & 63);
      int p = __shfl(epk, idx & 63);
      if (idx < cnt) {
        __half_raw hr; hr.x = (unsigned short)(sel(p) & 0xFFFFu);
        float e = __half2float(__half(hr));
        uint4 u = *(const uint4*)(base + (size_t)s * ROWH);
        fma8(u, e, acc);
      }
    }
  }

  // reduce across edge groups (keep sub)
#pragma unroll
  for (int o = LPE; o <= 32; o <<= 1) {
#pragma unroll
    for (int k = 0; k < 8; k++) acc[k] += __shfl_xor(acc[k], o);
  }
  for (int o = 32; o > 0; o >>= 1) {
    z0 += __shfl_xor(z0, o);
    if constexpr (H == 2) z1 += __shfl_xor(z1, o);
  }
  float inv;
  if constexpr (H == 2) inv = 1.0f / ((lane & 8) ? z1 : z0);
  else inv = 1.0f / z0;

  if (g == 0) {
    const float* bp = bias + sub * 8;
    float r[8];
#pragma unroll
    for (int k = 0; k < 8; k++) {
      r[k] = fmaf(acc[k], inv, bp[k]);
      if (RELU) r[k] = fmaxf(r[k], 0.f);
    }
    if constexpr (sizeof(OT) == 4) {
      float* op = (float*)OUT + (size_t)n * ROWH + sub * 8;
      ((float4*)op)[0] = make_float4(r[0], r[1], r[2], r[3]);
      ((float4*)op)[1] = make_float4(r[4], r[5], r[6], r[7]);
    } else {
      __half* op = (__half*)OUT + (size_t)n * ROWH + sub * 8;
      __half2 h0 = __floats2half2_rn(r[0], r[1]);
      __half2 h1 = __floats2half2_rn(r[2], r[3]);
      __half2 h2 = __floats2half2_rn(r[4], r[5]);
      __half2 h3 = __floats2half2_rn(r[6], r[7]);
      uint4 u;
      u.x = *(unsigned int*)&h0; u.y = *(unsigned int*)&h1;
      u.z = *(unsigned int*)&h2; u.w = *(unsigned int*)&h3;
      *(uint4*)op = u;
    }
  }
}

// ---------------- launch ----------------

static inline size_t alignup(size_t x) { return (x + 255) & ~(size_t)255; }

extern "C" void kernel_launch(void* const* d_in, const int* in_sizes, int n_in,
                              void* d_out, int out_size, void* d_ws, size_t ws_size,
                              hipStream_t stream) {
  const float* x    = (const float*)d_in[0];
  const int*   edges= (const int*)d_in[1];
  const float* W1   = (const float*)d_in[2];
  const float* as1w = (const float*)d_in[3];
  const float* ad1w = (const float*)d_in[4];
  const float* b1   = (const float*)d_in[5];
  const float* W2   = (const float*)d_in[6];
  const float* as2w = (const float*)d_in[7];
  const float* ad2w = (const float*)d_in[8];
  const float* b2   = (const float*)d_in[9];

  const int N = in_sizes[0] / 128;   // 50000
  const int E = in_sizes[1] / 2;     // 1600000
  const int* src = edges;
  const int* dst = edges + E;
  const int nbk = (N + 255) >> 8;    // 196 buckets

  char* p = (char*)d_ws;
  size_t off = 0;
  auto take = [&](size_t bytes) { char* r = p + off; off = alignup(off + bytes); return r; };
  __half* xph1 = (__half*)take((size_t)N * 128 * 2);  // row-major [N][128]
  __half* xph2 = (__half*)take((size_t)N * 64 * 2);
  __half* hbuf = (__half*)take((size_t)N * 128 * 2);
  __half* wt1  = (__half*)take((size_t)128 * 128 * 2);
  __half* wt2  = (__half*)take((size_t)64 * 128 * 2);
  float* as1   = (float*)take((size_t)N * 2 * 4);
  float* ad1   = (float*)take((size_t)N * 2 * 4);
  float* as2   = (float*)take((size_t)N * 4);
  float* ad2   = (float*)take((size_t)N * 4);
  int* offsets = (int*)take((size_t)(N + 1) * 4);
  int* csr_src = (int*)take((size_t)E * 4);
  unsigned int* binned = (unsigned int*)take((size_t)E * 4);
  int* bzero   = (int*)take((size_t)2 * (nbk + 1) * 4);
  int* bcount  = bzero;
  int* bcursor = bzero + (nbk + 1);
  (void)ws_size;

  constexpr int CHUNK = 8192;
  const int binBlocks = (E + CHUNK - 1) / CHUNK;
  const int gemmBlocks = (N + 63) / 64;

  hipMemsetAsync(bzero, 0, (size_t)2 * (nbk + 1) * 4, stream);
  bucket_hist<<<392, 256, 0, stream>>>(dst, bcount, E, nbk);
  bin_kernel<CHUNK><<<binBlocks, 256, 0, stream>>>(src, dst, bcount, bcursor, binned, E, nbk);
  build_kernel<12288><<<nbk, 256, 0, stream>>>(binned, bcount, offsets, csr_src, N, E, nbk);

  xpose_w<<<2, 256, 0, stream>>>(W1, W2, wt1, wt2);

  // layer 1 (H=2, C=64, ReLU): merged-head node kernel, row-major features
  gemm_att_mfma<128, 128, 2, float><<<gemmBlocks, 256, 0, stream>>>(
      x, wt1, as1w, ad1w, xph1, as1, ad1, N);
  node_kernel<2, true, __half><<<N, 64, 0, stream>>>(
      offsets, csr_src, as1, ad1, xph1, b1, hbuf, N);

  // layer 2 (H=1, C=64)
  gemm_att_mfma<128, 64, 1, __half><<<gemmBlocks, 256, 0, stream>>>(
      hbuf, wt2, as2w, ad2w, xph2, as2, ad2, N);
  node_kernel<1, false, float><<<N, 64, 0, stream>>>(
      offsets, csr_src, as2, ad2, xph2, b2, (float*)d_out, N);
}

// Round 11
// 170.017 us; speedup vs baseline: 1.1002x; 1.0327x over previous
//
#include <hip/hip_runtime.h>
#include <hip/hip_bf16.h>
#include <hip/hip_fp16.h>

// GAT 2-layer forward for MI355X — round 11.
// Changes vs round 10:
//  - xpose_w kernel deleted: gemm blocks stage W^T into LDS directly from the
//    fp32 W (coalesced read + in-LDS transpose); bucket_hist fused into the
//    gemm1 dispatch as extra blocks (independent work, overlaps ~9us).
//  - bin_kernel CHUNK 8192 -> 2048: 784 blocks (~3/CU) instead of 196 (1/CU)
//    to hide LDS-atomic scatter latency.
//  - node kernels unchanged from r10 (merged-head node1, 1 wave/node).

#define SLOPE 0.2f
static __device__ __forceinline__ float lrelu(float a) { return a > 0.f ? a : SLOPE * a; }

#define NBK_MAX 256  // max buckets (N <= 65536)

typedef _Float16 half8 __attribute__((ext_vector_type(8)));
typedef float f32x4 __attribute__((ext_vector_type(4)));

// ---------------- CSR build (bucketed) ----------------

template <int CHUNK>  // 2048 = 256 threads x 8
__global__ void bin_kernel(const int* __restrict__ src, const int* __restrict__ dst,
                           const int* __restrict__ bucket_count, int* __restrict__ bucket_cursor,
                           unsigned int* __restrict__ binned, int E, int nbk) {
  constexpr int PT = CHUNK / 256;
  __shared__ int hist[NBK_MAX];
  __shared__ int lbase[NBK_MAX];
  __shared__ int lcur[NBK_MAX];
  __shared__ int gpos[NBK_MAX];
  __shared__ unsigned int stage[CHUNK];
  __shared__ int sh[256];
  int t = threadIdx.x;
  int e0 = blockIdx.x * CHUNK;
  int cnt = min(CHUNK, E - e0);

  for (int i = t; i < nbk; i += 256) hist[i] = 0;
  __syncthreads();

  unsigned int pk[PT];
#pragma unroll
  for (int i = 0; i < PT; i++) {
    int e = e0 + t + i * 256;
    if (e < E) {
      int s = src[e], d = dst[e];
      int b = d >> 8;
      pk[i] = ((unsigned)b << 24) | ((unsigned)s << 8) | (unsigned)(d & 255);
      atomicAdd(&hist[b], 1);
    } else {
      pk[i] = 0xFFFFFFFFu;
    }
  }
  __syncthreads();

  int hv = (t < nbk) ? hist[t] : 0;
  sh[t] = hv;
  __syncthreads();
  for (int o = 1; o < 256; o <<= 1) {
    int u = (t >= o) ? sh[t - o] : 0;
    __syncthreads();
    sh[t] += u;
    __syncthreads();
  }
  if (t < nbk) {
    lbase[t] = sh[t] - hv;
    lcur[t] = sh[t] - hv;
  }
  __syncthreads();

  int gv = (t < nbk) ? bucket_count[t] : 0;
  sh[t] = gv;
  __syncthreads();
  for (int o = 1; o < 256; o <<= 1) {
    int u = (t >= o) ? sh[t - o] : 0;
    __syncthreads();
    sh[t] += u;
    __syncthreads();
  }
  if (t < nbk) {
    int gbase = sh[t] - gv;
    gpos[t] = hv ? (gbase + atomicAdd(&bucket_cursor[t], hv)) : 0;
  }
  __syncthreads();

#pragma unroll
  for (int i = 0; i < PT; i++) {
    if (pk[i] != 0xFFFFFFFFu) {
      int b = pk[i] >> 24;
      int lp = atomicAdd(&lcur[b], 1);
      stage[lp] = pk[i];
    }
  }
  __syncthreads();

  for (int i = t; i < cnt; i += 256) {
    unsigned int v = stage[i];
    int b = v >> 24;
    binned[gpos[b] + (i - lbase[b])] = v;
  }
}

template <int CAP>  // 12288
__global__ void build_kernel(const unsigned int* __restrict__ binned,
                             const int* __restrict__ bucket_count, int* __restrict__ offsets,
                             int* __restrict__ csr_src, int Nn, int Etot, int nbk) {
  __shared__ int nhist[256];
  __shared__ int sh[256];
  __shared__ int lcur[256];
  __shared__ int sbase, ssz;
  __shared__ unsigned short stage[CAP];
  int b = blockIdx.x;
  int t = threadIdx.x;

  int gv = (t < nbk) ? bucket_count[t] : 0;
  sh[t] = gv;
  __syncthreads();
  for (int o = 1; o < 256; o <<= 1) {
    int u = (t >= o) ? sh[t - o] : 0;
    __syncthreads();
    sh[t] += u;
    __syncthreads();
  }
  if (t == b) { sbase = sh[t] - gv; ssz = gv; }
  __syncthreads();
  int base = sbase;
  int sz = ssz;

  nhist[t] = 0;
  __syncthreads();
  for (int i = t; i < sz; i += 256) atomicAdd(&nhist[binned[base + i] & 255], 1);
  __syncthreads();

  int hv = nhist[t];
  sh[t] = hv;
  __syncthreads();
  for (int o = 1; o < 256; o <<= 1) {
    int u = (t >= o) ? sh[t - o] : 0;
    __syncthreads();
    sh[t] += u;
    __syncthreads();
  }
  int excl = sh[t] - hv;
  int node = (b << 8) + t;
  if (node < Nn) offsets[node] = base + excl;
  if (b == nbk - 1 && t == 0) offsets[Nn] = Etot;
  lcur[t] = excl;
  __syncthreads();

  if (sz <= CAP) {
    for (int i = t; i < sz; i += 256) {
      unsigned int v = binned[base + i];
      int lp = atomicAdd(&lcur[v & 255], 1);
      stage[lp] = (unsigned short)((v >> 8) & 0xFFFFu);
    }
    __syncthreads();
    for (int i = t; i < sz; i += 256) csr_src[base + i] = (int)stage[i];
  } else {
    for (int i = t; i < sz; i += 256) {
      unsigned int v = binned[base + i];
      int lp = atomicAdd(&lcur[v & 255], 1);
      csr_src[base + lp] = (int)((v >> 8) & 0xFFFFu);
    }
  }
}

// ---------------- MFMA GEMM + fused attention dots (+ optional fused hist) ----------------

// W is fp32 [K][NOUT] row-major (the original input); transposed+converted into
// LDS per block. If FUSE_HIST, blocks >= gemmBlocks run the dst bucket-histogram.
template <int K, int NOUT, int H, bool FUSE_HIST, typename AT>
__global__ __launch_bounds__(256) void gemm_att_mfma(
    const AT* __restrict__ A, const float* __restrict__ Wg,
    const float* __restrict__ att_s, const float* __restrict__ att_d,
    __half* __restrict__ Y, float* __restrict__ AS, float* __restrict__ AD, int M,
    int gemmBlocks, const int* __restrict__ dstArr, int* __restrict__ bcount,
    int E2, int histBlocks, int nbk) {
  constexpr int KK = K / 32;
  constexpr int NT = NOUT / 16;
  constexpr int NTH = NT / H;
  constexpr int LDW = K + 8;
  constexpr int LDY = NOUT + 8;
  __shared__ __half wts[NOUT * LDW];
  __shared__ __half ylds[4][16 * LDY];
  __shared__ int hh[NBK_MAX];

  int tid = threadIdx.x;

  if (FUSE_HIST && (int)blockIdx.x >= gemmBlocks) {
    int hb = blockIdx.x - gemmBlocks;
    for (int i = tid; i < nbk; i += 256) hh[i] = 0;
    __syncthreads();
    int stride = histBlocks * 256;
    for (int e = hb * 256 + tid; e < E2; e += stride)
      atomicAdd(&hh[dstArr[e] >> 8], 1);
    __syncthreads();
    for (int i = tid; i < nbk; i += 256)
      if (hh[i]) atomicAdd(&bcount[i], hh[i]);
    return;
  }

  int w = tid >> 6;
  int lane = tid & 63;
  int lrow = lane & 15;
  int lch = lane >> 4;
  int r0w = blockIdx.x * 64 + w * 16;
  bool active = (r0w < M);

  // stage W^T into LDS: coalesced fp32 read of W[k][c], write wts[c][k] fp16
  for (int idx = tid; idx < NOUT * K; idx += 256) {
    int k = idx / NOUT, c = idx - k * NOUT;
    wts[c * LDW + k] = __float2half(Wg[idx]);
  }
  __syncthreads();

  f32x4 acc[NT];
#pragma unroll
  for (int nt = 0; nt < NT; nt++) acc[nt] = (f32x4){0.f, 0.f, 0.f, 0.f};

  if (active) {
    half8 afrag[KK];
    if constexpr (sizeof(AT) == 4) {
      const float* arow = (const float*)A + (size_t)(r0w + lrow) * K + lch * 8;
#pragma unroll
      for (int kk = 0; kk < KK; kk++) {
        float4 v0 = *(const float4*)(arow + kk * 32);
        float4 v1 = *(const float4*)(arow + kk * 32 + 4);
        half8 a;
        a[0] = (_Float16)v0.x; a[1] = (_Float16)v0.y;
        a[2] = (_Float16)v0.z; a[3] = (_Float16)v0.w;
        a[4] = (_Float16)v1.x; a[5] = (_Float16)v1.y;
        a[6] = (_Float16)v1.z; a[7] = (_Float16)v1.w;
        afrag[kk] = a;
      }
    } else {
      const __half* arow = (const __half*)A + (size_t)(r0w + lrow) * K + lch * 8;
#pragma unroll
      for (int kk = 0; kk < KK; kk++) afrag[kk] = *(const half8*)(arow + kk * 32);
    }

#pragma unroll
    for (int kk = 0; kk < KK; kk++) {
#pragma unroll
      for (int nt = 0; nt < NT; nt++) {
        half8 b = *(const half8*)&wts[(nt * 16 + lrow) * LDW + kk * 32 + lch * 8];
        acc[nt] = __builtin_amdgcn_mfma_f32_16x16x32_f16(afrag[kk], b, acc[nt], 0, 0, 0);
      }
    }

    float asw[NT], adw[NT];
#pragma unroll
    for (int nt = 0; nt < NT; nt++) {
      asw[nt] = att_s[nt * 16 + lrow];
      adw[nt] = att_d[nt * 16 + lrow];
    }
#pragma unroll
    for (int h = 0; h < H; h++) {
#pragma unroll
      for (int reg = 0; reg < 4; reg++) {
        float ps = 0.f, pd = 0.f;
#pragma unroll
        for (int nt = h * NTH; nt < (h + 1) * NTH; nt++) {
          ps = fmaf(acc[nt][reg], asw[nt], ps);
          pd = fmaf(acc[nt][reg], adw[nt], pd);
        }
#pragma unroll
        for (int o = 1; o < 16; o <<= 1) {
          ps += __shfl_xor(ps, o);
          pd += __shfl_xor(pd, o);
        }
        if (lrow == 0) {
          int row = r0w + lch * 4 + reg;
          AS[row * H + h] = ps;
          AD[row * H + h] = pd;
        }
      }
    }

#pragma unroll
    for (int nt = 0; nt < NT; nt++) {
#pragma unroll
      for (int reg = 0; reg < 4; reg++) {
        ylds[w][(lch * 4 + reg) * LDY + nt * 16 + lrow] = __float2half(acc[nt][reg]);
      }
    }
  }
  __syncthreads();

  if (active) {
    constexpr int YCH = NOUT / 8;
    for (int idx = lane; idx < 16 * YCH; idx += 64) {
      int row = idx / YCH, ch = idx % YCH;
      uint4 v = *(const uint4*)&ylds[w][row * LDY + ch * 8];
      *(uint4*)(Y + (size_t)(r0w + row) * NOUT + ch * 8) = v;
    }
  }
}

// ---------------- node softmax + aggregate ----------------

static __device__ __forceinline__ void fma8(uint4 u, float e, float* __restrict__ acc) {
  float2 f0 = __half22float2(*(const __half2*)&u.x);
  float2 f1 = __half22float2(*(((const __half2*)&u.x) + 1));
  float2 f2 = __half22float2(*(const __half2*)&u.z);
  float2 f3 = __half22float2(*(((const __half2*)&u.z) + 1));
  acc[0] = fmaf(e, f0.x, acc[0]); acc[1] = fmaf(e, f0.y, acc[1]);
  acc[2] = fmaf(e, f1.x, acc[2]); acc[3] = fmaf(e, f1.y, acc[3]);
  acc[4] = fmaf(e, f2.x, acc[4]); acc[5] = fmaf(e, f2.y, acc[5]);
  acc[6] = fmaf(e, f3.x, acc[6]); acc[7] = fmaf(e, f3.y, acc[7]);
}

static __device__ __forceinline__ void pk4(uint4 u, unsigned ep, __half2* __restrict__ acc2) {
  __half2 e2 = *(const __half2*)&ep;
  acc2[0] = __hfma2(e2, *(const __half2*)&u.x, acc2[0]);
  acc2[1] = __hfma2(e2, *(((const __half2*)&u.x) + 1), acc2[1]);
  acc2[2] = __hfma2(e2, *(const __half2*)&u.z, acc2[2]);
  acc2[3] = __hfma2(e2, *(((const __half2*)&u.z) + 1), acc2[3]);
}

// One wave (64 thr) per node. H=2: 16 lanes/edge (lanes 0-7 head0, 8-15 head1),
// each edge visited once for both heads. H=1: 8 lanes/edge.
template <int H, bool RELU, typename OT>
__global__ void node_kernel(const int* __restrict__ offsets, const int* __restrict__ csr_src,
                            const float* __restrict__ AS, const float* __restrict__ AD,
                            const __half* __restrict__ XPH, const float* __restrict__ bias,
                            OT* __restrict__ OUT, int Nn) {
  constexpr int ROWH = H * 64;
  constexpr int LPE = (H == 2) ? 16 : 8;
  constexpr int G = 64 / LPE;
  int n = blockIdx.x;
  int lane = threadIdx.x & 63;
  int g = lane / LPE;
  int sub = lane & (LPE - 1);

  int beg = offsets[n], end = offsets[n + 1];
  int deg = end - beg;

  const __half* base = XPH + sub * 8;

  float acc[8];
#pragma unroll
  for (int k = 0; k < 8; k++) acc[k] = 0.f;
  float z0 = 0.f, z1 = 0.f;

  float ad0, ad1 = 0.f;
  if constexpr (H == 2) {
    float2 adn = ((const float2*)AD)[n];
    ad0 = adn.x; ad1 = adn.y;
  } else {
    ad0 = AD[n];
  }

  if constexpr (H == 2) {
    float2 asn = ((const float2*)AS)[n];
    float es0 = __expf(lrelu(asn.x + ad0));
    float es1 = __expf(lrelu(asn.y + ad1));
    if (g == 0) {
      uint4 u = *(const uint4*)(base + (size_t)n * ROWH);
      fma8(u, (lane & 8) ? es1 : es0, acc);
    }
    if (lane == 0) { z0 = es0; z1 = es1; }
  } else {
    float es = __expf(lrelu(AS[n] + ad0));
    if (g == 0) {
      uint4 u = *(const uint4*)(base + (size_t)n * ROWH);
      fma8(u, es, acc);
    }
    if (lane == 0) z0 = es;
  }

  for (int i0 = 0; i0 < deg; i0 += 64) {
    int cnt = min(64, deg - i0);
    int srcv = 0;
    int epk = 0;
    float ev0 = 0.f, ev1 = 0.f;
    if (lane < cnt) {
      srcv = csr_src[beg + i0 + lane];
      if constexpr (H == 2) {
        float2 asv = ((const float2*)AS)[srcv];
        ev0 = __expf(lrelu(asv.x + ad0));
        ev1 = __expf(lrelu(asv.y + ad1));
        __half h0 = __float2half(ev0), h1 = __float2half(ev1);
        epk = (int)(((unsigned)*(unsigned short*)&h1 << 16) | *(unsigned short*)&h0);
      } else {
        ev0 = __expf(lrelu(AS[srcv] + ad0));
        __half h0 = __float2half(ev0);
        unsigned short us = *(unsigned short*)&h0;
        epk = (int)(((unsigned)us << 16) | us);
      }
    }
    z0 += ev0;
    if constexpr (H == 2) z1 += ev1;

    auto sel = [&](int p) -> unsigned {
      unsigned short us;
      if constexpr (H == 2)
        us = (lane & 8) ? (unsigned short)((unsigned)p >> 16) : (unsigned short)((unsigned)p & 0xFFFFu);
      else
        us = (unsigned short)((unsigned)p & 0xFFFFu);
      return ((unsigned)us << 16) | us;
    };

    int j = 0;
    for (; j + 4 * G <= cnt; j += 4 * G) {
      int s0 = __shfl(srcv, j + g),         s1 = __shfl(srcv, j + G + g);
      int s2 = __shfl(srcv, j + 2 * G + g), s3 = __shfl(srcv, j + 3 * G + g);
      int p0 = __shfl(epk, j + g),          p1 = __shfl(epk, j + G + g);
      int p2 = __shfl(epk, j + 2 * G + g),  p3 = __shfl(epk, j + 3 * G + g);
      uint4 u0 = *(const uint4*)(base + (size_t)s0 * ROWH);
      uint4 u1 = *(const uint4*)(base + (size_t)s1 * ROWH);
      uint4 u2 = *(const uint4*)(base + (size_t)s2 * ROWH);
      uint4 u3 = *(const uint4*)(base + (size_t)s3 * ROWH);
      __half2 acc2[4];
      acc2[0] = __half2(__half(0.f), __half(0.f));
      acc2[1] = acc2[0]; acc2[2] = acc2[0]; acc2[3] = acc2[0];
      pk4(u0, sel(p0), acc2);
      pk4(u1, sel(p1), acc2);
      pk4(u2, sel(p2), acc2);
      pk4(u3, sel(p3), acc2);
#pragma unroll
      for (int k = 0; k < 4; k++) {
        float2 f = __half22float2(acc2[k]);
        acc[2 * k] += f.x;
        acc[2 * k + 1] += f.y;
      }
    }
    for (; j + G <= cnt; j += G) {
      int s = __shfl(srcv, j + g);
      int p = __shfl(epk, j + g);
      __half_raw hr; hr.x = (unsigned short)(sel(p) & 0xFFFFu);
      float e = __half2float(__half(hr));
      uint4 u = *(const uint4*)(base + (size_t)s * ROWH);
      fma8(u, e, acc);
    }
    if (j < cnt) {
      int idx = j + g;
      int s = __shfl(srcv, idx & 63);
      int p = __shfl(epk, idx & 63);
      if (idx < cnt) {
        __half_raw hr; hr.x = (unsigned short)(sel(p) & 0xFFFFu);
        float e = __half2float(__half(hr));
        uint4 u = *(const uint4*)(base + (size_t)s * ROWH);
        fma8(u, e, acc);
      }
    }
  }

#pragma unroll
  for (int o = LPE; o <= 32; o <<= 1) {
#pragma unroll
    for (int k = 0; k < 8; k++) acc[k] += __shfl_xor(acc[k], o);
  }
  for (int o = 32; o > 0; o >>= 1) {
    z0 += __shfl_xor(z0, o);
    if constexpr (H == 2) z1 += __shfl_xor(z1, o);
  }
  float inv;
  if constexpr (H == 2) inv = 1.0f / ((lane & 8) ? z1 : z0);
  else inv = 1.0f / z0;

  if (g == 0) {
    const float* bp = bias + sub * 8;
    float r[8];
#pragma unroll
    for (int k = 0; k < 8; k++) {
      r[k] = fmaf(acc[k], inv, bp[k]);
      if (RELU) r[k] = fmaxf(r[k], 0.f);
    }
    if constexpr (sizeof(OT) == 4) {
      float* op = (float*)OUT + (size_t)n * ROWH + sub * 8;
      ((float4*)op)[0] = make_float4(r[0], r[1], r[2], r[3]);
      ((float4*)op)[1] = make_float4(r[4], r[5], r[6], r[7]);
    } else {
      __half* op = (__half*)OUT + (size_t)n * ROWH + sub * 8;
      __half2 h0 = __floats2half2_rn(r[0], r[1]);
      __half2 h1 = __floats2half2_rn(r[2], r[3]);
      __half2 h2 = __floats2half2_rn(r[4], r[5]);
      __half2 h3 = __floats2half2_rn(r[6], r[7]);
      uint4 u;
      u.x = *(unsigned int*)&h0; u.y = *(unsigned int*)&h1;
      u.z = *(unsigned int*)&h2; u.w = *(unsigned int*)&h3;
      *(uint4*)op = u;
    }
  }
}

// ---------------- launch ----------------

static inline size_t alignup(size_t x) { return (x + 255) & ~(size_t)255; }

extern "C" void kernel_launch(void* const* d_in, const int* in_sizes, int n_in,
                              void* d_out, int out_size, void* d_ws, size_t ws_size,
                              hipStream_t stream) {
  const float* x    = (const float*)d_in[0];
  const int*   edges= (const int*)d_in[1];
  const float* W1   = (const float*)d_in[2];
  const float* as1w = (const float*)d_in[3];
  const float* ad1w = (const float*)d_in[4];
  const float* b1   = (const float*)d_in[5];
  const float* W2   = (const float*)d_in[6];
  const float* as2w = (const float*)d_in[7];
  const float* ad2w = (const float*)d_in[8];
  const float* b2   = (const float*)d_in[9];

  const int N = in_sizes[0] / 128;   // 50000
  const int E = in_sizes[1] / 2;     // 1600000
  const int* src = edges;
  const int* dst = edges + E;
  const int nbk = (N + 255) >> 8;    // 196 buckets

  char* p = (char*)d_ws;
  size_t off = 0;
  auto take = [&](size_t bytes) { char* r = p + off; off = alignup(off + bytes); return r; };
  __half* xph1 = (__half*)take((size_t)N * 128 * 2);  // row-major [N][128]
  __half* xph2 = (__half*)take((size_t)N * 64 * 2);
  __half* hbuf = (__half*)take((size_t)N * 128 * 2);
  float* as1   = (float*)take((size_t)N * 2 * 4);
  float* ad1   = (float*)take((size_t)N * 2 * 4);
  float* as2   = (float*)take((size_t)N * 4);
  float* ad2   = (float*)take((size_t)N * 4);
  int* offsets = (int*)take((size_t)(N + 1) * 4);
  int* csr_src = (int*)take((size_t)E * 4);
  unsigned int* binned = (unsigned int*)take((size_t)E * 4);
  int* bzero   = (int*)take((size_t)2 * (nbk + 1) * 4);
  int* bcount  = bzero;
  int* bcursor = bzero + (nbk + 1);
  (void)ws_size;

  constexpr int CHUNK = 2048;
  const int binBlocks = (E + CHUNK - 1) / CHUNK;
  const int gemmBlocks = (N + 63) / 64;   // 782
  const int histBlocks = 392;

  hipMemsetAsync(bzero, 0, (size_t)2 * (nbk + 1) * 4, stream);

  // MEGA dispatch: gemm1 (blocks [0,gemmBlocks)) + dst bucket-histogram
  // (blocks [gemmBlocks, gemmBlocks+histBlocks)) run concurrently.
  gemm_att_mfma<128, 128, 2, true, float><<<gemmBlocks + histBlocks, 256, 0, stream>>>(
      x, W1, as1w, ad1w, xph1, as1, ad1, N,
      gemmBlocks, dst, bcount, E, histBlocks, nbk);

  bin_kernel<CHUNK><<<binBlocks, 256, 0, stream>>>(src, dst, bcount, bcursor, binned, E, nbk);
  build_kernel<12288><<<nbk, 256, 0, stream>>>(binned, bcount, offsets, csr_src, N, E, nbk);

  // layer 1 node aggregation (merged heads)
  node_kernel<2, true, __half><<<N, 64, 0, stream>>>(
      offsets, csr_src, as1, ad1, xph1, b1, hbuf, N);

  // layer 2
  gemm_att_mfma<128, 64, 1, false, __half><<<gemmBlocks, 256, 0, stream>>>(
      hbuf, W2, as2w, ad2w, xph2, as2, ad2, N,
      gemmBlocks, nullptr, nullptr, 0, 0, nbk);
  node_kernel<1, false, float><<<N, 64, 0, stream>>>(
      offsets, csr_src, as2, ad2, xph2, b2, (float*)d_out, N);
}

// Round 12
// 143.485 us; speedup vs baseline: 1.3036x; 1.1849x over previous
//
#include <hip/hip_runtime.h>
#include <hip/hip_bf16.h>
#include <hip/hip_fp16.h>

// GAT 2-layer forward for MI355X — round 12.
// Changes vs round 11:
//  - Histogram kernel DELETED. bin uses fixed-stride bucket slabs
//    (CAPB=10240/bucket) + atomic cursors -> no dependence on a prior count
//    pass -> bin blocks fused into the gemm1 dispatch (true overlap).
//  - build recovers CSR bases by scanning the 196 cursor counts in-block.
//  - gemm LDS: ylds aliased onto wts (wts dead after MFMA; +1 barrier),
//    34KB static LDS -> 4 blocks/CU for both gemm and bin branch blocks.
//  - node kernels unchanged (merged-head node1, 1 wave/node).

#define SLOPE 0.2f
static __device__ __forceinline__ float lrelu(float a) { return a > 0.f ? a : SLOPE * a; }

#define NBK_MAX 256  // max buckets (N <= 65536)

typedef _Float16 half8 __attribute__((ext_vector_type(8)));
typedef float f32x4 __attribute__((ext_vector_type(4)));

// ---------------- MEGA: MFMA GEMM + fused attention dots (+ fused bin) ----------------

// W is fp32 [K][NOUT] row-major; transposed+converted into LDS per block.
// If FUSE_BIN, blocks >= gemmBlocks run the edge-binning pass into fixed-stride
// bucket slabs: binned[b*capb + atomic-reserved range].
template <int K, int NOUT, int H, bool FUSE_BIN, int CHUNK, typename AT>
__global__ __launch_bounds__(256) void gemm_bin_mfma(
    const AT* __restrict__ A, const float* __restrict__ Wg,
    const float* __restrict__ att_s, const float* __restrict__ att_d,
    __half* __restrict__ Y, float* __restrict__ AS, float* __restrict__ AD,
    int M, int gemmBlocks,
    const int* __restrict__ srcArr, const int* __restrict__ dstArr,
    int* __restrict__ cursor, unsigned int* __restrict__ binned,
    int E2, int nbk, int capb) {
  constexpr int KK = K / 32;
  constexpr int NT = NOUT / 16;
  constexpr int NTH = NT / H;
  constexpr int LDW = K + 8;
  constexpr int LDY = NOUT + 8;
  constexpr int WTS_B = NOUT * LDW * 2;
  constexpr int YLDS_B = 4 * 16 * LDY * 2;
  constexpr int GEMM_B = (WTS_B > YLDS_B) ? WTS_B : YLDS_B;  // ylds aliases wts
  constexpr int BIN_B = 5 * 256 * 4 + CHUNK * 4;
  constexpr int SMEM_B = (FUSE_BIN && BIN_B > GEMM_B) ? BIN_B : GEMM_B;
  __shared__ __align__(16) char smem[SMEM_B];

  int tid = threadIdx.x;

  if constexpr (FUSE_BIN) {
    if ((int)blockIdx.x >= gemmBlocks) {
      // ---- bin branch ----
      int* hist = (int*)smem;
      int* lbase = hist + 256;
      int* lcur = lbase + 256;
      int* gpos = lcur + 256;
      int* sh = gpos + 256;
      unsigned int* stage = (unsigned int*)(sh + 256);
      constexpr int PT = CHUNK / 256;
      int t = tid;
      int bb = blockIdx.x - gemmBlocks;
      int e0 = bb * CHUNK;
      int cnt = min(CHUNK, E2 - e0);

      hist[t] = 0;
      __syncthreads();

      unsigned int pk[PT];
#pragma unroll
      for (int i = 0; i < PT; i++) {
        int e = e0 + t + i * 256;
        if (e < E2) {
          int s = srcArr[e], d = dstArr[e];
          int b = d >> 8;
          pk[i] = ((unsigned)b << 24) | ((unsigned)s << 8) | (unsigned)(d & 255);
          atomicAdd(&hist[b], 1);
        } else {
          pk[i] = 0xFFFFFFFFu;
        }
      }
      __syncthreads();

      // exclusive scan of local hist
      int hv = hist[t];
      sh[t] = hv;
      __syncthreads();
      for (int o = 1; o < 256; o <<= 1) {
        int u = (t >= o) ? sh[t - o] : 0;
        __syncthreads();
        sh[t] += u;
        __syncthreads();
      }
      lbase[t] = sh[t] - hv;
      lcur[t] = sh[t] - hv;
      gpos[t] = hv ? (t * capb + atomicAdd(&cursor[t], hv)) : 0;
      __syncthreads();

      // local scatter into stage (sorted by bucket)
#pragma unroll
      for (int i = 0; i < PT; i++) {
        if (pk[i] != 0xFFFFFFFFu) {
          int b = pk[i] >> 24;
          int lp = atomicAdd(&lcur[b], 1);
          stage[lp] = pk[i];
        }
      }
      __syncthreads();

      // coalesced slab writes
      for (int i = t; i < cnt; i += 256) {
        unsigned int v = stage[i];
        int b = v >> 24;
        binned[gpos[b] + (i - lbase[b])] = v;
      }
      return;
    }
  }

  // ---- gemm branch ----
  __half* wts = (__half*)smem;
  __half(*ylds)[16 * LDY] = (__half(*)[16 * LDY])smem;  // aliases wts (time-disjoint)

  int w = tid >> 6;
  int lane = tid & 63;
  int lrow = lane & 15;
  int lch = lane >> 4;
  int r0w = blockIdx.x * 64 + w * 16;
  bool active = (r0w < M);

  // stage W^T into LDS: coalesced fp32 read of W[k][c], write wts[c][k] fp16
  for (int idx = tid; idx < NOUT * K; idx += 256) {
    int k = idx / NOUT, c = idx - k * NOUT;
    wts[c * LDW + k] = __float2half(Wg[idx]);
  }
  __syncthreads();

  f32x4 acc[NT];
#pragma unroll
  for (int nt = 0; nt < NT; nt++) acc[nt] = (f32x4){0.f, 0.f, 0.f, 0.f};

  if (active) {
    half8 afrag[KK];
    if constexpr (sizeof(AT) == 4) {
      const float* arow = (const float*)A + (size_t)(r0w + lrow) * K + lch * 8;
#pragma unroll
      for (int kk = 0; kk < KK; kk++) {
        float4 v0 = *(const float4*)(arow + kk * 32);
        float4 v1 = *(const float4*)(arow + kk * 32 + 4);
        half8 a;
        a[0] = (_Float16)v0.x; a[1] = (_Float16)v0.y;
        a[2] = (_Float16)v0.z; a[3] = (_Float16)v0.w;
        a[4] = (_Float16)v1.x; a[5] = (_Float16)v1.y;
        a[6] = (_Float16)v1.z; a[7] = (_Float16)v1.w;
        afrag[kk] = a;
      }
    } else {
      const __half* arow = (const __half*)A + (size_t)(r0w + lrow) * K + lch * 8;
#pragma unroll
      for (int kk = 0; kk < KK; kk++) afrag[kk] = *(const half8*)(arow + kk * 32);
    }

#pragma unroll
    for (int kk = 0; kk < KK; kk++) {
#pragma unroll
      for (int nt = 0; nt < NT; nt++) {
        half8 b = *(const half8*)&wts[(nt * 16 + lrow) * LDW + kk * 32 + lch * 8];
        acc[nt] = __builtin_amdgcn_mfma_f32_16x16x32_f16(afrag[kk], b, acc[nt], 0, 0, 0);
      }
    }

    // attention dots from fp32 accumulators (exact)
    float asw[NT], adw[NT];
#pragma unroll
    for (int nt = 0; nt < NT; nt++) {
      asw[nt] = att_s[nt * 16 + lrow];
      adw[nt] = att_d[nt * 16 + lrow];
    }
#pragma unroll
    for (int h = 0; h < H; h++) {
#pragma unroll
      for (int reg = 0; reg < 4; reg++) {
        float ps = 0.f, pd = 0.f;
#pragma unroll
        for (int nt = h * NTH; nt < (h + 1) * NTH; nt++) {
          ps = fmaf(acc[nt][reg], asw[nt], ps);
          pd = fmaf(acc[nt][reg], adw[nt], pd);
        }
#pragma unroll
        for (int o = 1; o < 16; o <<= 1) {
          ps += __shfl_xor(ps, o);
          pd += __shfl_xor(pd, o);
        }
        if (lrow == 0) {
          int row = r0w + lch * 4 + reg;
          AS[row * H + h] = ps;
          AD[row * H + h] = pd;
        }
      }
    }
  }

  __syncthreads();  // wts dead from here; ylds may overwrite

  if (active) {
#pragma unroll
    for (int nt = 0; nt < NT; nt++) {
#pragma unroll
      for (int reg = 0; reg < 4; reg++) {
        ylds[w][(lch * 4 + reg) * LDY + nt * 16 + lrow] = __float2half(acc[nt][reg]);
      }
    }
  }
  __syncthreads();

  if (active) {
    constexpr int YCH = NOUT / 8;
    for (int idx = lane; idx < 16 * YCH; idx += 64) {
      int row = idx / YCH, ch = idx % YCH;
      uint4 v = *(const uint4*)&ylds[w][row * LDY + ch * 8];
      *(uint4*)(Y + (size_t)(r0w + row) * NOUT + ch * 8) = v;
    }
  }
}

// ---------------- build: bucket slabs -> exact CSR ----------------

template <int CAP>  // 12288
__global__ void build_kernel(const unsigned int* __restrict__ binned,
                             const int* __restrict__ cursor, int* __restrict__ offsets,
                             int* __restrict__ csr_src, int Nn, int Etot, int nbk, int capb) {
  __shared__ int nhist[256];
  __shared__ int sh[256];
  __shared__ int lcur[256];
  __shared__ int sbase, ssz;
  __shared__ unsigned short stage[CAP];
  int b = blockIdx.x;
  int t = threadIdx.x;

  // scan final bucket counts (cursor) -> this bucket's CSR base/size
  int gv = (t < nbk) ? cursor[t] : 0;
  sh[t] = gv;
  __syncthreads();
  for (int o = 1; o < 256; o <<= 1) {
    int u = (t >= o) ? sh[t - o] : 0;
    __syncthreads();
    sh[t] += u;
    __syncthreads();
  }
  if (t == b) { sbase = sh[t] - gv; ssz = gv; }
  __syncthreads();
  int csrbase = sbase;
  int sz = ssz;
  int binbase = b * capb;

  nhist[t] = 0;
  __syncthreads();
  for (int i = t; i < sz; i += 256) atomicAdd(&nhist[binned[binbase + i] & 255], 1);
  __syncthreads();

  int hv = nhist[t];
  sh[t] = hv;
  __syncthreads();
  for (int o = 1; o < 256; o <<= 1) {
    int u = (t >= o) ? sh[t - o] : 0;
    __syncthreads();
    sh[t] += u;
    __syncthreads();
  }
  int excl = sh[t] - hv;
  int node = (b << 8) + t;
  if (node < Nn) offsets[node] = csrbase + excl;
  if (b == nbk - 1 && t == 0) offsets[Nn] = Etot;
  lcur[t] = excl;
  __syncthreads();

  if (sz <= CAP) {
    for (int i = t; i < sz; i += 256) {
      unsigned int v = binned[binbase + i];
      int lp = atomicAdd(&lcur[v & 255], 1);
      stage[lp] = (unsigned short)((v >> 8) & 0xFFFFu);
    }
    __syncthreads();
    for (int i = t; i < sz; i += 256) csr_src[csrbase + i] = (int)stage[i];
  } else {
    for (int i = t; i < sz; i += 256) {
      unsigned int v = binned[binbase + i];
      int lp = atomicAdd(&lcur[v & 255], 1);
      csr_src[csrbase + lp] = (int)((v >> 8) & 0xFFFFu);
    }
  }
}

// ---------------- node softmax + aggregate ----------------

static __device__ __forceinline__ void fma8(uint4 u, float e, float* __restrict__ acc) {
  float2 f0 = __half22float2(*(const __half2*)&u.x);
  float2 f1 = __half22float2(*(((const __half2*)&u.x) + 1));
  float2 f2 = __half22float2(*(const __half2*)&u.z);
  float2 f3 = __half22float2(*(((const __half2*)&u.z) + 1));
  acc[0] = fmaf(e, f0.x, acc[0]); acc[1] = fmaf(e, f0.y, acc[1]);
  acc[2] = fmaf(e, f1.x, acc[2]); acc[3] = fmaf(e, f1.y, acc[3]);
  acc[4] = fmaf(e, f2.x, acc[4]); acc[5] = fmaf(e, f2.y, acc[5]);
  acc[6] = fmaf(e, f3.x, acc[6]); acc[7] = fmaf(e, f3.y, acc[7]);
}

static __device__ __forceinline__ void pk4(uint4 u, unsigned ep, __half2* __restrict__ acc2) {
  __half2 e2 = *(const __half2*)&ep;
  acc2[0] = __hfma2(e2, *(const __half2*)&u.x, acc2[0]);
  acc2[1] = __hfma2(e2, *(((const __half2*)&u.x) + 1), acc2[1]);
  acc2[2] = __hfma2(e2, *(const __half2*)&u.z, acc2[2]);
  acc2[3] = __hfma2(e2, *(((const __half2*)&u.z) + 1), acc2[3]);
}

// One wave (64 thr) per node. H=2: 16 lanes/edge (lanes 0-7 head0, 8-15 head1),
// each edge visited once for both heads. H=1: 8 lanes/edge.
template <int H, bool RELU, typename OT>
__global__ void node_kernel(const int* __restrict__ offsets, const int* __restrict__ csr_src,
                            const float* __restrict__ AS, const float* __restrict__ AD,
                            const __half* __restrict__ XPH, const float* __restrict__ bias,
                            OT* __restrict__ OUT, int Nn) {
  constexpr int ROWH = H * 64;
  constexpr int LPE = (H == 2) ? 16 : 8;
  constexpr int G = 64 / LPE;
  int n = blockIdx.x;
  int lane = threadIdx.x & 63;
  int g = lane / LPE;
  int sub = lane & (LPE - 1);

  int beg = offsets[n], end = offsets[n + 1];
  int deg = end - beg;

  const __half* base = XPH + sub * 8;

  float acc[8];
#pragma unroll
  for (int k = 0; k < 8; k++) acc[k] = 0.f;
  float z0 = 0.f, z1 = 0.f;

  float ad0, ad1 = 0.f;
  if constexpr (H == 2) {
    float2 adn = ((const float2*)AD)[n];
    ad0 = adn.x; ad1 = adn.y;
  } else {
    ad0 = AD[n];
  }

  if constexpr (H == 2) {
    float2 asn = ((const float2*)AS)[n];
    float es0 = __expf(lrelu(asn.x + ad0));
    float es1 = __expf(lrelu(asn.y + ad1));
    if (g == 0) {
      uint4 u = *(const uint4*)(base + (size_t)n * ROWH);
      fma8(u, (lane & 8) ? es1 : es0, acc);
    }
    if (lane == 0) { z0 = es0; z1 = es1; }
  } else {
    float es = __expf(lrelu(AS[n] + ad0));
    if (g == 0) {
      uint4 u = *(const uint4*)(base + (size_t)n * ROWH);
      fma8(u, es, acc);
    }
    if (lane == 0) z0 = es;
  }

  for (int i0 = 0; i0 < deg; i0 += 64) {
    int cnt = min(64, deg - i0);
    int srcv = 0;
    int epk = 0;
    float ev0 = 0.f, ev1 = 0.f;
    if (lane < cnt) {
      srcv = csr_src[beg + i0 + lane];
      if constexpr (H == 2) {
        float2 asv = ((const float2*)AS)[srcv];
        ev0 = __expf(lrelu(asv.x + ad0));
        ev1 = __expf(lrelu(asv.y + ad1));
        __half h0 = __float2half(ev0), h1 = __float2half(ev1);
        epk = (int)(((unsigned)*(unsigned short*)&h1 << 16) | *(unsigned short*)&h0);
      } else {
        ev0 = __expf(lrelu(AS[srcv] + ad0));
        __half h0 = __float2half(ev0);
        unsigned short us = *(unsigned short*)&h0;
        epk = (int)(((unsigned)us << 16) | us);
      }
    }
    z0 += ev0;
    if constexpr (H == 2) z1 += ev1;

    auto sel = [&](int p) -> unsigned {
      unsigned short us;
      if constexpr (H == 2)
        us = (lane & 8) ? (unsigned short)((unsigned)p >> 16) : (unsigned short)((unsigned)p & 0xFFFFu);
      else
        us = (unsigned short)((unsigned)p & 0xFFFFu);
      return ((unsigned)us << 16) | us;
    };

    int j = 0;
    for (; j + 4 * G <= cnt; j += 4 * G) {
      int s0 = __shfl(srcv, j + g),         s1 = __shfl(srcv, j + G + g);
      int s2 = __shfl(srcv, j + 2 * G + g), s3 = __shfl(srcv, j + 3 * G + g);
      int p0 = __shfl(epk, j + g),          p1 = __shfl(epk, j + G + g);
      int p2 = __shfl(epk, j + 2 * G + g),  p3 = __shfl(epk, j + 3 * G + g);
      uint4 u0 = *(const uint4*)(base + (size_t)s0 * ROWH);
      uint4 u1 = *(const uint4*)(base + (size_t)s1 * ROWH);
      uint4 u2 = *(const uint4*)(base + (size_t)s2 * ROWH);
      uint4 u3 = *(const uint4*)(base + (size_t)s3 * ROWH);
      __half2 acc2[4];
      acc2[0] = __half2(__half(0.f), __half(0.f));
      acc2[1] = acc2[0]; acc2[2] = acc2[0]; acc2[3] = acc2[0];
      pk4(u0, sel(p0), acc2);
      pk4(u1, sel(p1), acc2);
      pk4(u2, sel(p2), acc2);
      pk4(u3, sel(p3), acc2);
#pragma unroll
      for (int k = 0; k < 4; k++) {
        float2 f = __half22float2(acc2[k]);
        acc[2 * k] += f.x;
        acc[2 * k + 1] += f.y;
      }
    }
    for (; j + G <= cnt; j += G) {
      int s = __shfl(srcv, j + g);
      int p = __shfl(epk, j + g);
      __half_raw hr; hr.x = (unsigned short)(sel(p) & 0xFFFFu);
      float e = __half2float(__half(hr));
      uint4 u = *(const uint4*)(base + (size_t)s * ROWH);
      fma8(u, e, acc);
    }
    if (j < cnt) {
      int idx = j + g;
      int s = __shfl(srcv, idx & 63);
      int p = __shfl(epk, idx & 63);
      if (idx < cnt) {
        __half_raw hr; hr.x = (unsigned short)(sel(p) & 0xFFFFu);
        float e = __half2float(__half(hr));
        uint4 u = *(const uint4*)(base + (size_t)s * ROWH);
        fma8(u, e, acc);
      }
    }
  }

#pragma unroll
  for (int o = LPE; o <= 32; o <<= 1) {
#pragma unroll
    for (int k = 0; k < 8; k++) acc[k] += __shfl_xor(acc[k], o);
  }
  for (int o = 32; o > 0; o >>= 1) {
    z0 += __shfl_xor(z0, o);
    if constexpr (H == 2) z1 += __shfl_xor(z1, o);
  }
  float inv;
  if constexpr (H == 2) inv = 1.0f / ((lane & 8) ? z1 : z0);
  else inv = 1.0f / z0;

  if (g == 0) {
    const float* bp = bias + sub * 8;
    float r[8];
#pragma unroll
    for (int k = 0; k < 8; k++) {
      r[k] = fmaf(acc[k], inv, bp[k]);
      if (RELU) r[k] = fmaxf(r[k], 0.f);
    }
    if constexpr (sizeof(OT) == 4) {
      float* op = (float*)OUT + (size_t)n * ROWH + sub * 8;
      ((float4*)op)[0] = make_float4(r[0], r[1], r[2], r[3]);
      ((float4*)op)[1] = make_float4(r[4], r[5], r[6], r[7]);
    } else {
      __half* op = (__half*)OUT + (size_t)n * ROWH + sub * 8;
      __half2 h0 = __floats2half2_rn(r[0], r[1]);
      __half2 h1 = __floats2half2_rn(r[2], r[3]);
      __half2 h2 = __floats2half2_rn(r[4], r[5]);
      __half2 h3 = __floats2half2_rn(r[6], r[7]);
      uint4 u;
      u.x = *(unsigned int*)&h0; u.y = *(unsigned int*)&h1;
      u.z = *(unsigned int*)&h2; u.w = *(unsigned int*)&h3;
      *(uint4*)op = u;
    }
  }
}

// ---------------- launch ----------------

static inline size_t alignup(size_t x) { return (x + 255) & ~(size_t)255; }

extern "C" void kernel_launch(void* const* d_in, const int* in_sizes, int n_in,
                              void* d_out, int out_size, void* d_ws, size_t ws_size,
                              hipStream_t stream) {
  const float* x    = (const float*)d_in[0];
  const int*   edges= (const int*)d_in[1];
  const float* W1   = (const float*)d_in[2];
  const float* as1w = (const float*)d_in[3];
  const float* ad1w = (const float*)d_in[4];
  const float* b1   = (const float*)d_in[5];
  const float* W2   = (const float*)d_in[6];
  const float* as2w = (const float*)d_in[7];
  const float* ad2w = (const float*)d_in[8];
  const float* b2   = (const float*)d_in[9];

  const int N = in_sizes[0] / 128;   // 50000
  const int E = in_sizes[1] / 2;     // 1600000
  const int* src = edges;
  const int* dst = edges + E;
  const int nbk = (N + 255) >> 8;    // 196 buckets

  constexpr int CHUNK = 2048;
  constexpr int CAPB = 10240;        // slab capacity per bucket (mean 8163, 23 sigma margin)

  char* p = (char*)d_ws;
  size_t off = 0;
  auto take = [&](size_t bytes) { char* r = p + off; off = alignup(off + bytes); return r; };
  __half* xph1 = (__half*)take((size_t)N * 128 * 2);  // row-major [N][128]
  __half* xph2 = (__half*)take((size_t)N * 64 * 2);
  __half* hbuf = (__half*)take((size_t)N * 128 * 2);
  float* as1   = (float*)take((size_t)N * 2 * 4);
  float* ad1   = (float*)take((size_t)N * 2 * 4);
  float* as2   = (float*)take((size_t)N * 4);
  float* ad2   = (float*)take((size_t)N * 4);
  int* offsets = (int*)take((size_t)(N + 1) * 4);
  int* csr_src = (int*)take((size_t)E * 4);
  unsigned int* binned = (unsigned int*)take((size_t)nbk * CAPB * 4);
  int* cursor  = (int*)take((size_t)NBK_MAX * 4);
  (void)ws_size;

  const int binBlocks = (E + CHUNK - 1) / CHUNK;   // 782
  const int gemmBlocks = (N + 63) / 64;            // 782

  hipMemsetAsync(cursor, 0, (size_t)NBK_MAX * 4, stream);

  // MEGA dispatch: gemm1 blocks [0,gemmBlocks) + bin blocks [gemmBlocks, +binBlocks)
  gemm_bin_mfma<128, 128, 2, true, CHUNK, float><<<gemmBlocks + binBlocks, 256, 0, stream>>>(
      x, W1, as1w, ad1w, xph1, as1, ad1, N, gemmBlocks,
      src, dst, cursor, binned, E, nbk, CAPB);

  build_kernel<12288><<<nbk, 256, 0, stream>>>(binned, cursor, offsets, csr_src, N, E, nbk, CAPB);

  // layer 1 node aggregation (merged heads)
  node_kernel<2, true, __half><<<N, 64, 0, stream>>>(
      offsets, csr_src, as1, ad1, xph1, b1, hbuf, N);

  // layer 2
  gemm_bin_mfma<128, 64, 1, false, CHUNK, __half><<<gemmBlocks, 256, 0, stream>>>(
      hbuf, W2, as2w, ad2w, xph2, as2, ad2, N, gemmBlocks,
      nullptr, nullptr, nullptr, nullptr, 0, nbk, CAPB);
  node_kernel<1, false, float><<<N, 64, 0, stream>>>(
      offsets, csr_src, as2, ad2, xph2, b2, (float*)d_out, N);
}